// Round 14
// baseline (168.322 us; speedup 1.0000x reference)
//
#include <hip/hip_runtime.h>
#include <math.h>

typedef int i32x4 __attribute__((ext_vector_type(4)));
typedef int i32x16 __attribute__((ext_vector_type(16)));

#define CC 248
#define MM 65536
#define NN 1024

__device__ __forceinline__ float fexp2(float x) { return __builtin_amdgcn_exp2f(x); }

// ws: A_tiled [2][256 tiles][pl 2][kg 16][row 256][16]   = 67,108,864 B
//     B_tiled [2][32 ntiles][pl 2][kg 16][col 32][16]    =  1,048,576 B
//     partials [2][1024][64 mrange] float4                =  2,097,152 B

// ---------------- convB: pixel descriptors -> i8 hi/lo planes, tiled ----------------
__global__ __launch_bounds__(512)
void convB_kernel(const float* __restrict__ dense, char* __restrict__ Ag) {
    __shared__ char at[2][16][128][16];       // 64 KB
    __shared__ float scr[4][128];
    const int bid = blockIdx.x;               // 0..1023
    const int fb  = bid >> 9;                 // 0..1 -> frame 2*fb
    const int p0  = (bid & 511) * 128;
    const int tid = threadIdx.x;
    const int row = tid & 127;
    const int q   = tid >> 7;                 // 0..3 -> channels q*64..q*64+63

    const float* dptr = dense + (size_t)(2 * fb) * CC * MM + p0 + row;
    float v[64];
    float ss = 0.f;
#pragma unroll
    for (int i = 0; i < 64; ++i) {
        int c = q * 64 + i;
        float x = (c < CC) ? dptr[(size_t)c * MM] : 0.f;
        v[i] = x;
        ss += x * x;
    }
    scr[q][row] = ss;
    __syncthreads();
    float inv = 32768.0f / fmaxf(sqrtf(scr[0][row] + scr[1][row] + scr[2][row] + scr[3][row]), 1e-12f);

#pragma unroll
    for (int j = 0; j < 16; ++j) {
        unsigned w1 = 0, w0 = 0;
#pragma unroll
        for (int t = 0; t < 4; ++t) {
            float qv = fminf(fmaxf(rintf(v[j * 4 + t] * inv), -32768.f), 32639.f);
            int af = (int)qv;
            int a1 = (af + 128) >> 8;
            int a0 = af - (a1 << 8);
            w1 |= (unsigned)(a1 & 255) << (8 * t);
            w0 |= (unsigned)(a0 & 255) << (8 * t);
        }
        int c0 = q * 64 + j * 4;
        int kg = c0 >> 4, dw = (c0 >> 2) & 3;
        *(unsigned*)&at[0][kg][row][dw * 4] = w1;
        *(unsigned*)&at[1][kg][row][dw * 4] = w0;
    }
    __syncthreads();

    const int tile = p0 >> 8, rhalf = (p0 >> 7) & 1;
    char* outb = Ag + (size_t)(fb * 256 + tile) * 131072;
#pragma unroll
    for (int it = 0; it < 8; ++it) {
        int id = tid + it * 512;              // 0..4095 16B chunks
        int pl = id >> 11, kg = (id >> 7) & 15, r2 = id & 127;
        i32x4 vv = *(const i32x4*)&at[pl][kg][r2][0];
        *(i32x4*)&outb[(size_t)pl * 65536 + kg * 4096 + (rhalf * 128 + r2) * 16] = vv;
    }
}

// ---------------- convA: keypoint descriptors -> i8 hi/lo planes, 32-col tiles ----------------
__global__ __launch_bounds__(256)
void convA_kernel(const float* __restrict__ kdesc, char* __restrict__ Bg) {
    __shared__ char bt[2][16][32][16];        // 16 KB
    __shared__ float scr[8][32];
    const int bid = blockIdx.x;               // 0..63
    const int b   = bid >> 5;
    const int nt  = bid & 31;
    const int n0  = nt * 32;
    const int tid = threadIdx.x;
    const int col = tid & 31;
    const int q   = tid >> 5;                 // 0..7 -> channels q*31..q*31+30

    const float* kp = kdesc + (size_t)(2 * b + 1) * CC * NN + n0 + col;
    float ss = 0.f;
    for (int i = 0; i < 31; ++i) {
        int c = q * 31 + i;
        float v = kp[(size_t)c * NN];
        ss += v * v;
    }
    scr[q][col] = ss;
    __syncthreads();
    float tot = 0.f;
#pragma unroll
    for (int k = 0; k < 8; ++k) tot += scr[k][col];
    float inv = 32768.0f / fmaxf(sqrtf(tot), 1e-12f);
    if (tid < 64) {                            // zero k-pad c=248..255
        int pl = tid >> 5, c2 = tid & 31;
        *(long*)&bt[pl][15][c2][8] = 0L;
    }
    __syncthreads();
    for (int i = 0; i < 31; ++i) {
        int c = q * 31 + i;
        float qq = fminf(fmaxf(rintf(kp[(size_t)c * NN] * inv), -32768.f), 32639.f);
        int af = (int)qq;
        int a1 = (af + 128) >> 8;
        int a0 = af - (a1 << 8);
        bt[0][c >> 4][col][c & 15] = (char)a1;
        bt[1][c >> 4][col][c & 15] = (char)a0;
    }
    __syncthreads();
    char* outb = Bg + (size_t)(b * 32 + nt) * 16384;
    const char* src = &bt[0][0][0][0];
#pragma unroll
    for (int it = 0; it < 4; ++it) {
        int id = tid + it * 256;              // 0..1023 16B chunks
        *(i32x4*)&outb[(size_t)id * 16] = *(const i32x4*)&src[(size_t)id * 16];
    }
}

// ---------------- fused i8 MFMA GEMM: all-register, barrier-free, LDS-free ----------------
// 2048 independent wave-tasks: (b, nblk 0..15 [64 n], mrange 0..63 [1024 m rows]).
// Per wave: bc = k1 full-K in regs; per slice (64 m x 32 k): A frags + k0 frags
// loaded L2->regs with 1-slice-ahead ping-pong prefetch (compiler-counted vmcnt).
__global__ __launch_bounds__(256, 2)
void gemm_kernel(const char* __restrict__ Ag, const char* __restrict__ Bg,
                 float* __restrict__ partials) {
    const int bid  = blockIdx.x;              // 0..511
    const int xcd  = bid & 7;
    const int rest = bid >> 3;                // 0..63
    const int sub  = rest & 3;
    const int panel = xcd + 8 * (rest >> 2);  // 0..127 : A-panel sharers -> same XCD
    const int b      = panel >> 6;
    const int mrange = panel & 63;            // 1024 rows each

    const int lane = threadIdx.x & 63;
    const int w    = threadIdx.x >> 6;        // 0..3
    const int nblk = sub * 4 + w;             // 0..15 (64 n each)
    const int lrow = lane & 31;
    const int lhi  = lane >> 5;

    const char* abase = Ag + ((size_t)b * 256 + mrange * 4) * 131072;  // 4 tiles of 256 rows
    const char* bb    = Bg + (size_t)(b * 32 + nblk * 2) * 16384;      // 2 n-tiles

    // ---- bc: k1 (hi plane), full K, 2 n-tiles -> 64 regs ----
    i32x4 bc[8][2];
#pragma unroll
    for (int kk = 0; kk < 8; ++kk)
#pragma unroll
        for (int bp = 0; bp < 2; ++bp)
            bc[kk][bp] = *(const i32x4*)(bb + bp * 16384 + (kk * 2 + lhi) * 512 + lrow * 16);

    // ping-pong fragment regs
    i32x4 aS[2][2][2];   // [slot][pl][ap]
    i32x4 b0S[2][2];     // [slot][bp]

    // A frag address: tile(mt>>2)*131072 + pl*65536 + (ks*2+lhi)*4096 + ((mt&3)*64 + ap*32 + lrow)*16
    const int va = lhi * 4096 + lrow * 16;    // per-lane part
    auto LOADA = [&](int slot, int mtn, int ksn) {
        const char* sA = abase + (size_t)(mtn >> 2) * 131072 + (mtn & 3) * 1024 + ksn * 8192;
#pragma unroll
        for (int pl = 0; pl < 2; ++pl)
#pragma unroll
            for (int ap = 0; ap < 2; ++ap)
                aS[slot][pl][ap] = *(const i32x4*)(sA + pl * 65536 + va + ap * 512);
    };
    auto LOADB0 = [&](int slot, int ksn) {
#pragma unroll
        for (int bp = 0; bp < 2; ++bp)
            b0S[slot][bp] = *(const i32x4*)(bb + bp * 16384 + 8192 + (ksn * 2 + lhi) * 512 + lrow * 16);
    };

    i32x16 accH[2][2], accX[2][2];
#pragma unroll
    for (int ap = 0; ap < 2; ++ap)
#pragma unroll
        for (int bp = 0; bp < 2; ++bp) { accH[ap][bp] = (i32x16)(0); accX[ap][bp] = (i32x16)(0); }
    float rm[2], rz[2], rsu[2], rsv[2];
#pragma unroll
    for (int bp = 0; bp < 2; ++bp) { rm[bp] = -INFINITY; rz[bp] = 0.f; rsu[bp] = 0.f; rsv[bp] = 0.f; }

    // score*log2(e) = (65536*H + 256*X) * 100*log2(e) / 2^30
    const float S2 = 100.0f * 1.4426950408889634f / 1073741824.0f;
    const float cH = 65536.0f * S2;
    const float cX = 256.0f * S2;

    LOADB0(0, 0);
    LOADA(0, 0, 0);

    for (int mt = 0; mt < 16; ++mt) {
#pragma unroll
        for (int ks = 0; ks < 8; ++ks) {
            const int slot = ks & 1;
            // prefetch slice s+1 into the other slot (overrun at the very end reads
            // valid-but-unused ws bytes; never consumed)
            {
                const int ksn = (ks + 1) & 7;
                const int mtn = (ks == 7) ? mt + 1 : mt;
                LOADB0(slot ^ 1, ksn);
                LOADA(slot ^ 1, (mtn < 16) ? mtn : 15, ksn);
            }
            __builtin_amdgcn_s_setprio(1);
#pragma unroll
            for (int ap = 0; ap < 2; ++ap)
#pragma unroll
                for (int bp = 0; bp < 2; ++bp) {
                    accH[ap][bp] = __builtin_amdgcn_mfma_i32_32x32x32_i8(aS[slot][0][ap], bc[ks][bp],   accH[ap][bp], 0, 0, 0);
                    accX[ap][bp] = __builtin_amdgcn_mfma_i32_32x32x32_i8(aS[slot][0][ap], b0S[slot][bp], accX[ap][bp], 0, 0, 0);
                    accX[ap][bp] = __builtin_amdgcn_mfma_i32_32x32x32_i8(aS[slot][1][ap], bc[ks][bp],   accX[ap][bp], 0, 0, 0);
                }
            __builtin_amdgcn_s_setprio(0);
        }

        // ---- epilogue for m-tile mt (64 rows x this wave's 64 n) ----
        const int mbase = mrange * 1024 + mt * 64;
        const float ub0 = (float)((mbase & 255) + 4 * lhi);
        const float ub1 = ub0 + 32.0f;
        const float vcoord = (float)(mbase >> 8);
#pragma unroll
        for (int bp = 0; bp < 2; ++bp) {
            int hm = accH[0][bp][0];
#pragma unroll
            for (int ap = 0; ap < 2; ++ap)
#pragma unroll
                for (int r = 0; r < 16; ++r) {
                    int h = accH[ap][bp][r];
                    hm = (h > hm) ? h : hm;
                }
            const float bx = (float)hm * cH;
            float tz0 = 0.f, tz1 = 0.f, tsur = 0.f;
#pragma unroll
            for (int ap = 0; ap < 2; ++ap)
#pragma unroll
                for (int r = 0; r < 16; ++r) {
                    int dH = accH[ap][bp][r] - hm;                 // exact
                    float e = fexp2(fmaf((float)dH, cH, (float)accX[ap][bp][r] * cX));
                    if (ap == 0) tz0 += e; else tz1 += e;
                    tsur = fmaf(e, (float)((r & 3) + 8 * (r >> 2)), tsur);
                }
            float tzz = tz0 + tz1;
            float tsu = fmaf(ub0, tz0, fmaf(ub1, tz1, tsur));
            float tsv = vcoord * tzz;
            float nm = fmaxf(rm[bp], bx);
            float f1 = fexp2(rm[bp] - nm), f2 = fexp2(bx - nm);
            rz[bp]  = rz[bp]  * f1 + tzz * f2;
            rsu[bp] = rsu[bp] * f1 + tsu * f2;
            rsv[bp] = rsv[bp] * f1 + tsv * f2;
            rm[bp]  = nm;
#pragma unroll
            for (int ap = 0; ap < 2; ++ap) { accH[ap][bp] = (i32x16)(0); accX[ap][bp] = (i32x16)(0); }
        }
    }

    // ---- merge lane <-> lane+32 (same column, other row half), write partials ----
#pragma unroll
    for (int bp = 0; bp < 2; ++bp) {
        float m2  = __shfl_xor(rm[bp], 32, 64);
        float z2  = __shfl_xor(rz[bp], 32, 64);
        float su2 = __shfl_xor(rsu[bp], 32, 64);
        float sv2 = __shfl_xor(rsv[bp], 32, 64);
        float nm = fmaxf(rm[bp], m2);
        float f1 = fexp2(rm[bp] - nm), f2 = fexp2(m2 - nm);
        rz[bp]  = rz[bp]  * f1 + z2  * f2;
        rsu[bp] = rsu[bp] * f1 + su2 * f2;
        rsv[bp] = rsv[bp] * f1 + sv2 * f2;
        rm[bp]  = nm;
    }
    if (lane < 32) {
#pragma unroll
        for (int bp = 0; bp < 2; ++bp) {
            int n = nblk * 64 + bp * 32 + lrow;
            size_t idxp = ((size_t)b * NN + n) * 64 + mrange;
            ((float4*)partials)[idxp] = make_float4(rm[bp], rz[bp], rsu[bp], rsv[bp]);
        }
    }
}

// ---------------- combine: one wave per (b,n) row, 64 partials each ----------------
__global__ __launch_bounds__(256)
void combine_kernel(const float* __restrict__ partials,
                    const float* __restrict__ kscores,
                    const float* __restrict__ times,
                    float* __restrict__ out) {
    const int wg   = blockIdx.x * 4 + (threadIdx.x >> 6);  // 0..2047 = (b, n)
    const int lane = threadIdx.x & 63;
    const int b = wg >> 10, n = wg & 1023;
    const float4* pp = (const float4*)partials + (size_t)wg * 64;

    float4 p = pp[lane];
    float m = p.x, z = p.y, su = p.z, sv = p.w;
#pragma unroll
    for (int mask = 32; mask >= 1; mask >>= 1) {
        float m2  = __shfl_xor(m, mask, 64);
        float z2  = __shfl_xor(z, mask, 64);
        float su2 = __shfl_xor(su, mask, 64);
        float sv2 = __shfl_xor(sv, mask, 64);
        float nm = fmaxf(m, m2);
        float f1 = fexp2(m - nm), f2 = fexp2(m2 - nm);
        z = z * f1 + z2 * f2; su = su * f1 + su2 * f2; sv = sv * f1 + sv2 * f2; m = nm;
    }

    if (lane == 0) {
        float u = su / z, v = sv / z;
        out[(size_t)wg * 2 + 0] = u;
        out[(size_t)wg * 2 + 1] = v;
        out[4096 + wg] = kscores[(size_t)(2 * b + 1) * NN + n];
        if (wg == 0) { out[6144] = 1.0f; out[6145] = 3.0f; }

        const float* timg = times + (size_t)(2 * b) * MM;
        float u0 = fminf(fmaxf(floorf(u), 0.f), 255.f);
        float v0 = fminf(fmaxf(floorf(v), 0.f), 255.f);
        float u1 = fminf(u0 + 1.f, 255.f);
        float v1 = fminf(v0 + 1.f, 255.f);
        float au = u - u0, av = v - v0;
        int u0i = (int)u0, u1i = (int)u1, v0i = (int)v0, v1i = (int)v1;
        float t00 = timg[v0i * 256 + u0i], t01 = timg[v0i * 256 + u1i];
        float t10 = timg[v1i * 256 + u0i], t11 = timg[v1i * 256 + u1i];
        float t = t00 * (1.f - au) * (1.f - av) + t01 * au * (1.f - av)
                + t10 * (1.f - au) * av + t11 * au * av;
        out[6146 + wg] = t;
    }
}

extern "C" void kernel_launch(void* const* d_in, const int* in_sizes, int n_in,
                              void* d_out, int out_size, void* d_ws, size_t ws_size,
                              hipStream_t stream) {
    const float* kscores = (const float*)d_in[0];
    const float* kdesc   = (const float*)d_in[1];
    const float* dense   = (const float*)d_in[2];
    const float* times   = (const float*)d_in[3];
    float* out = (float*)d_out;

    char* Ag = (char*)d_ws;                                   // 67,108,864 B
    char* Bg = Ag + (size_t)2 * 256 * 131072;                 //  1,048,576 B
    float* partials = (float*)(Bg + (size_t)2 * 32 * 16384);  //  2,097,152 B

    hipLaunchKernelGGL(convB_kernel,   dim3(1024), dim3(512), 0, stream, dense, Ag);
    hipLaunchKernelGGL(convA_kernel,   dim3(64),   dim3(256), 0, stream, kdesc, Bg);
    hipLaunchKernelGGL(gemm_kernel,    dim3(512),  dim3(256), 0, stream, Ag, Bg, partials);
    hipLaunchKernelGGL(combine_kernel, dim3(512),  dim3(256), 0, stream, partials, kscores, times, out);
}

// Round 15
// 149.172 us; speedup vs baseline: 1.1284x; 1.1284x over previous
//
#include <hip/hip_runtime.h>
#include <math.h>

typedef int i32x4 __attribute__((ext_vector_type(4)));
typedef int i32x16 __attribute__((ext_vector_type(16)));

#define CC 248
#define MM 65536
#define NN 1024

__device__ __forceinline__ float fexp2(float x) { return __builtin_amdgcn_exp2f(x); }

// ws: A_tiled [2][256 tiles][pl 2][kg 16][row 256][16]   = 67,108,864 B
//     B_tiled [2][32 ntiles][pl 2][kg 16][col 32][16]    =  1,048,576 B
//     partials [2][1024][64 mchunk] float4                =  2,097,152 B

// ---------------- convB: pixel descriptors -> i8 hi/lo planes, tiled ----------------
__global__ __launch_bounds__(512)
void convB_kernel(const float* __restrict__ dense, char* __restrict__ Ag) {
    __shared__ char at[2][16][128][16];       // 64 KB
    __shared__ float scr[4][128];
    const int bid = blockIdx.x;               // 0..1023
    const int fb  = bid >> 9;                 // 0..1 -> frame 2*fb
    const int p0  = (bid & 511) * 128;
    const int tid = threadIdx.x;
    const int row = tid & 127;
    const int q   = tid >> 7;                 // 0..3 -> channels q*64..q*64+63

    const float* dptr = dense + (size_t)(2 * fb) * CC * MM + p0 + row;
    float v[64];
    float ss = 0.f;
#pragma unroll
    for (int i = 0; i < 64; ++i) {
        int c = q * 64 + i;
        float x = (c < CC) ? dptr[(size_t)c * MM] : 0.f;
        v[i] = x;
        ss += x * x;
    }
    scr[q][row] = ss;
    __syncthreads();
    float inv = 32768.0f / fmaxf(sqrtf(scr[0][row] + scr[1][row] + scr[2][row] + scr[3][row]), 1e-12f);

#pragma unroll
    for (int j = 0; j < 16; ++j) {
        unsigned w1 = 0, w0 = 0;
#pragma unroll
        for (int t = 0; t < 4; ++t) {
            float qv = fminf(fmaxf(rintf(v[j * 4 + t] * inv), -32768.f), 32639.f);
            int af = (int)qv;
            int a1 = (af + 128) >> 8;
            int a0 = af - (a1 << 8);
            w1 |= (unsigned)(a1 & 255) << (8 * t);
            w0 |= (unsigned)(a0 & 255) << (8 * t);
        }
        int c0 = q * 64 + j * 4;
        int kg = c0 >> 4, dw = (c0 >> 2) & 3;
        *(unsigned*)&at[0][kg][row][dw * 4] = w1;
        *(unsigned*)&at[1][kg][row][dw * 4] = w0;
    }
    __syncthreads();

    const int tile = p0 >> 8, rhalf = (p0 >> 7) & 1;
    char* outb = Ag + (size_t)(fb * 256 + tile) * 131072;
#pragma unroll
    for (int it = 0; it < 8; ++it) {
        int id = tid + it * 512;              // 0..4095 16B chunks
        int pl = id >> 11, kg = (id >> 7) & 15, r2 = id & 127;
        i32x4 vv = *(const i32x4*)&at[pl][kg][r2][0];
        *(i32x4*)&outb[(size_t)pl * 65536 + kg * 4096 + (rhalf * 128 + r2) * 16] = vv;
    }
}

// ---------------- convA: keypoint descriptors -> i8 hi/lo planes, 32-col tiles ----------------
__global__ __launch_bounds__(256)
void convA_kernel(const float* __restrict__ kdesc, char* __restrict__ Bg) {
    __shared__ char bt[2][16][32][16];        // 16 KB
    __shared__ float scr[8][32];
    const int bid = blockIdx.x;               // 0..63
    const int b   = bid >> 5;
    const int nt  = bid & 31;
    const int n0  = nt * 32;
    const int tid = threadIdx.x;
    const int col = tid & 31;
    const int q   = tid >> 5;                 // 0..7 -> channels q*31..q*31+30

    const float* kp = kdesc + (size_t)(2 * b + 1) * CC * NN + n0 + col;
    float ss = 0.f;
    for (int i = 0; i < 31; ++i) {
        int c = q * 31 + i;
        float v = kp[(size_t)c * NN];
        ss += v * v;
    }
    scr[q][col] = ss;
    __syncthreads();
    float tot = 0.f;
#pragma unroll
    for (int k = 0; k < 8; ++k) tot += scr[k][col];
    float inv = 32768.0f / fmaxf(sqrtf(tot), 1e-12f);
    if (tid < 64) {                            // zero k-pad c=248..255
        int pl = tid >> 5, c2 = tid & 31;
        *(long*)&bt[pl][15][c2][8] = 0L;
    }
    __syncthreads();
    for (int i = 0; i < 31; ++i) {
        int c = q * 31 + i;
        float qq = fminf(fmaxf(rintf(kp[(size_t)c * NN] * inv), -32768.f), 32639.f);
        int af = (int)qq;
        int a1 = (af + 128) >> 8;
        int a0 = af - (a1 << 8);
        bt[0][c >> 4][col][c & 15] = (char)a1;
        bt[1][c >> 4][col][c & 15] = (char)a0;
    }
    __syncthreads();
    char* outb = Bg + (size_t)(b * 32 + nt) * 16384;
    const char* src = &bt[0][0][0][0];
#pragma unroll
    for (int it = 0; it < 4; ++it) {
        int id = tid + it * 256;              // 0..1023 16B chunks
        *(i32x4*)&outb[(size_t)id * 16] = *(const i32x4*)&src[(size_t)id * 16];
    }
}

// ---------------- fused i8 MFMA GEMM: m=32/wave, B fully in regs, tiny A ring in LDS ----
// Block: 4 waves, BN=256 (64 n per wave), BM=1024 (32 mt of 32 rows), 128 phases (64k each).
// LDS: A ring 3 x 4096 [pl2][kgh2][row32 x lane-half][16] = 12 KB total.
__global__ __launch_bounds__(256, 2)
void gemm_kernel(const char* __restrict__ Ag, const char* __restrict__ Bg,
                 float* __restrict__ partials) {
    __shared__ char lds[12288];

    const int bid  = blockIdx.x;              // 0..511
    const int xcd  = bid & 7;
    const int rest = bid >> 3;                // 0..63
    const int nchunk = rest & 3;
    const int pid  = xcd + 8 * (rest >> 2);   // 0..127 : A-panel sharers -> same XCD
    const int b      = pid >> 6;
    const int mchunk = pid & 63;              // BM = 1024

    const int lane = threadIdx.x & 63;
    const int w    = threadIdx.x >> 6;        // 0..3
    const int lrow = lane & 31;
    const int lhi  = lane >> 5;

    const char* atile0 = Ag + ((size_t)b * 256 + mchunk * 4) * 131072;  // 4 tiles of 256 rows
    const char* bb     = Bg + (size_t)(b * 32 + nchunk * 8 + w * 2) * 16384;  // wave's 2 n-tiles

    // ---- bc: BOTH planes, full K, 2 n-tiles -> 128 regs ----
    i32x4 bc[8][2][2];                         // [kk][pl][bp]
#pragma unroll
    for (int kk = 0; kk < 8; ++kk)
#pragma unroll
        for (int pl = 0; pl < 2; ++pl)
#pragma unroll
            for (int bp = 0; bp < 2; ++bp)
                bc[kk][pl][bp] = *(const i32x4*)(bb + bp * 16384 + pl * 8192
                                                 + (kk * 2 + lhi) * 512 + lrow * 16);

    // staging: wave w owns chunk (pl=w>>1, kgh=w&1); 4 x 1KB = one 32m x 64k x 2pl phase-slice
    auto ISSUE = [&](int p, int slotOff) {
        const int mtn = p >> 2, kq = p & 3;
        const int tile = mtn >> 3, row0 = (mtn & 7) * 32;
        const char* src = atile0 + (size_t)tile * 131072 + (w >> 1) * 65536
                        + (kq * 4 + (w & 1) * 2 + lhi) * 4096 + (row0 + lrow) * 16;
        char* dst = &lds[slotOff + (w >> 1) * 2048 + (w & 1) * 1024];
        __builtin_amdgcn_global_load_lds(
            (const __attribute__((address_space(1))) void*)src,
            (__attribute__((address_space(3))) void*)dst, 16, 0, 0);
    };

    i32x16 accH[2], accX[2];
#pragma unroll
    for (int bp = 0; bp < 2; ++bp) { accH[bp] = (i32x16)(0); accX[bp] = (i32x16)(0); }
    float rm[2], rz[2], rsu[2], rsv[2];
#pragma unroll
    for (int bp = 0; bp < 2; ++bp) { rm[bp] = -INFINITY; rz[bp] = 0.f; rsu[bp] = 0.f; rsv[bp] = 0.f; }

    // score*log2(e) = (65536*H + 256*X) * 100*log2(e) / 2^30
    const float S2 = 100.0f * 1.4426950408889634f / 1073741824.0f;
    const float cH = 65536.0f * S2;
    const float cX = 256.0f * S2;

    ISSUE(0, 0);
    ISSUE(1, 4096);
    int slotR = 0, slotW = 8192;               // phase p: read p%3, ISSUE(p+2) -> (p+2)%3

    for (int mt = 0; mt < 32; ++mt) {
#pragma unroll
        for (int kq = 0; kq < 4; ++kq) {
            const int p = mt * 4 + kq;
            if (p < 127) asm volatile("s_waitcnt vmcnt(1)" ::: "memory");  // phase-p slice done
            else         asm volatile("s_waitcnt vmcnt(0)" ::: "memory");
            asm volatile("s_barrier" ::: "memory");
            if (p + 2 < 128) ISSUE(p + 2, slotW);

#pragma unroll
            for (int j = 0; j < 2; ++j) {      // two K=32 steps
                const int kk = kq * 2 + j;
                i32x4 a1 = *(const i32x4*)&lds[slotR + j * 1024 + lhi * 512 + lrow * 16];
                i32x4 a0 = *(const i32x4*)&lds[slotR + 2048 + j * 1024 + lhi * 512 + lrow * 16];
                __builtin_amdgcn_s_setprio(1);
#pragma unroll
                for (int bp = 0; bp < 2; ++bp) {
                    accH[bp] = __builtin_amdgcn_mfma_i32_32x32x32_i8(a1, bc[kk][0][bp], accH[bp], 0, 0, 0);
                    accX[bp] = __builtin_amdgcn_mfma_i32_32x32x32_i8(a1, bc[kk][1][bp], accX[bp], 0, 0, 0);
                    accX[bp] = __builtin_amdgcn_mfma_i32_32x32x32_i8(a0, bc[kk][0][bp], accX[bp], 0, 0, 0);
                }
                __builtin_amdgcn_s_setprio(0);
            }
            slotR = (slotR == 8192) ? 0 : slotR + 4096;
            slotW = (slotW == 8192) ? 0 : slotW + 4096;
        }

        // ---- epilogue for m-tile mt (32 rows x this wave's 64 n) ----
        const int mbase = mchunk * 1024 + mt * 32;
        const float ub = (float)((mbase & 255) + 4 * lhi);
        const float vcoord = (float)(mbase >> 8);
#pragma unroll
        for (int bp = 0; bp < 2; ++bp) {
            int hm = accH[bp][0];
#pragma unroll
            for (int r = 0; r < 16; ++r) {
                int h = accH[bp][r];
                hm = (h > hm) ? h : hm;
            }
            const float bx = (float)hm * cH;
            float tz = 0.f, tsur = 0.f;
#pragma unroll
            for (int r = 0; r < 16; ++r) {
                int dH = accH[bp][r] - hm;                     // exact
                float e = fexp2(fmaf((float)dH, cH, (float)accX[bp][r] * cX));
                tz += e;
                tsur = fmaf(e, (float)((r & 3) + 8 * (r >> 2)), tsur);
            }
            float tsu = fmaf(ub, tz, tsur);
            float tsv = vcoord * tz;
            float nm = fmaxf(rm[bp], bx);
            float f1 = fexp2(rm[bp] - nm), f2 = fexp2(bx - nm);
            rz[bp]  = rz[bp]  * f1 + tz  * f2;
            rsu[bp] = rsu[bp] * f1 + tsu * f2;
            rsv[bp] = rsv[bp] * f1 + tsv * f2;
            rm[bp]  = nm;
            accH[bp] = (i32x16)(0); accX[bp] = (i32x16)(0);
        }
    }

    // ---- merge lane <-> lane+32 (same column, other row half), write partials ----
#pragma unroll
    for (int bp = 0; bp < 2; ++bp) {
        float m2  = __shfl_xor(rm[bp], 32, 64);
        float z2  = __shfl_xor(rz[bp], 32, 64);
        float su2 = __shfl_xor(rsu[bp], 32, 64);
        float sv2 = __shfl_xor(rsv[bp], 32, 64);
        float nm = fmaxf(rm[bp], m2);
        float f1 = fexp2(rm[bp] - nm), f2 = fexp2(m2 - nm);
        rz[bp]  = rz[bp]  * f1 + z2  * f2;
        rsu[bp] = rsu[bp] * f1 + su2 * f2;
        rsv[bp] = rsv[bp] * f1 + sv2 * f2;
        rm[bp]  = nm;
    }
    if (lane < 32) {
#pragma unroll
        for (int bp = 0; bp < 2; ++bp) {
            int n = nchunk * 256 + w * 64 + bp * 32 + lrow;
            size_t idxp = ((size_t)b * NN + n) * 64 + mchunk;
            ((float4*)partials)[idxp] = make_float4(rm[bp], rz[bp], rsu[bp], rsv[bp]);
        }
    }
}

// ---------------- combine: one wave per (b,n) row, 64 partials each ----------------
__global__ __launch_bounds__(256)
void combine_kernel(const float* __restrict__ partials,
                    const float* __restrict__ kscores,
                    const float* __restrict__ times,
                    float* __restrict__ out) {
    const int wg   = blockIdx.x * 4 + (threadIdx.x >> 6);  // 0..2047 = (b, n)
    const int lane = threadIdx.x & 63;
    const int b = wg >> 10, n = wg & 1023;
    const float4* pp = (const float4*)partials + (size_t)wg * 64;

    float4 p = pp[lane];
    float m = p.x, z = p.y, su = p.z, sv = p.w;
#pragma unroll
    for (int mask = 32; mask >= 1; mask >>= 1) {
        float m2  = __shfl_xor(m, mask, 64);
        float z2  = __shfl_xor(z, mask, 64);
        float su2 = __shfl_xor(su, mask, 64);
        float sv2 = __shfl_xor(sv, mask, 64);
        float nm = fmaxf(m, m2);
        float f1 = fexp2(m - nm), f2 = fexp2(m2 - nm);
        z = z * f1 + z2 * f2; su = su * f1 + su2 * f2; sv = sv * f1 + sv2 * f2; m = nm;
    }

    if (lane == 0) {
        float u = su / z, v = sv / z;
        out[(size_t)wg * 2 + 0] = u;
        out[(size_t)wg * 2 + 1] = v;
        out[4096 + wg] = kscores[(size_t)(2 * b + 1) * NN + n];
        if (wg == 0) { out[6144] = 1.0f; out[6145] = 3.0f; }

        const float* timg = times + (size_t)(2 * b) * MM;
        float u0 = fminf(fmaxf(floorf(u), 0.f), 255.f);
        float v0 = fminf(fmaxf(floorf(v), 0.f), 255.f);
        float u1 = fminf(u0 + 1.f, 255.f);
        float v1 = fminf(v0 + 1.f, 255.f);
        float au = u - u0, av = v - v0;
        int u0i = (int)u0, u1i = (int)u1, v0i = (int)v0, v1i = (int)v1;
        float t00 = timg[v0i * 256 + u0i], t01 = timg[v0i * 256 + u1i];
        float t10 = timg[v1i * 256 + u0i], t11 = timg[v1i * 256 + u1i];
        float t = t00 * (1.f - au) * (1.f - av) + t01 * au * (1.f - av)
                + t10 * (1.f - au) * av + t11 * au * av;
        out[6146 + wg] = t;
    }
}

extern "C" void kernel_launch(void* const* d_in, const int* in_sizes, int n_in,
                              void* d_out, int out_size, void* d_ws, size_t ws_size,
                              hipStream_t stream) {
    const float* kscores = (const float*)d_in[0];
    const float* kdesc   = (const float*)d_in[1];
    const float* dense   = (const float*)d_in[2];
    const float* times   = (const float*)d_in[3];
    float* out = (float*)d_out;

    char* Ag = (char*)d_ws;                                   // 67,108,864 B
    char* Bg = Ag + (size_t)2 * 256 * 131072;                 //  1,048,576 B
    float* partials = (float*)(Bg + (size_t)2 * 32 * 16384);  //  2,097,152 B

    hipLaunchKernelGGL(convB_kernel,   dim3(1024), dim3(512), 0, stream, dense, Ag);
    hipLaunchKernelGGL(convA_kernel,   dim3(64),   dim3(256), 0, stream, kdesc, Bg);
    hipLaunchKernelGGL(gemm_kernel,    dim3(512),  dim3(256), 0, stream, Ag, Bg, partials);
    hipLaunchKernelGGL(combine_kernel, dim3(512),  dim3(256), 0, stream, partials, kscores, times, out);
}

// Round 16
// 136.719 us; speedup vs baseline: 1.2312x; 1.0911x over previous
//
#include <hip/hip_runtime.h>
#include <math.h>

typedef int i32x4 __attribute__((ext_vector_type(4)));
typedef int i32x16 __attribute__((ext_vector_type(16)));

#define CC 248
#define MM 65536
#define NN 1024

__device__ __forceinline__ float fexp2(float x) { return __builtin_amdgcn_exp2f(x); }

// ws: A_tiled [2][256 tiles][pl 2][kg 16][row 256][16]   = 67,108,864 B
//     B_tiled [2][32 ntiles][pl 2][kg 16][col 32][16]    =  1,048,576 B
//     partials [2][1024][64 mchunk] float4                =  2,097,152 B

// ---------------- convB: pixel descriptors -> i8 hi/lo planes, tiled ----------------
__global__ __launch_bounds__(512)
void convB_kernel(const float* __restrict__ dense, char* __restrict__ Ag) {
    __shared__ char at[2][16][128][16];       // 64 KB
    __shared__ float scr[4][128];
    const int bid = blockIdx.x;               // 0..1023
    const int fb  = bid >> 9;                 // 0..1 -> frame 2*fb
    const int p0  = (bid & 511) * 128;
    const int tid = threadIdx.x;
    const int row = tid & 127;
    const int q   = tid >> 7;                 // 0..3 -> channels q*64..q*64+63

    const float* dptr = dense + (size_t)(2 * fb) * CC * MM + p0 + row;
    float v[64];
    float ss = 0.f;
#pragma unroll
    for (int i = 0; i < 64; ++i) {
        int c = q * 64 + i;
        float x = (c < CC) ? dptr[(size_t)c * MM] : 0.f;
        v[i] = x;
        ss += x * x;
    }
    scr[q][row] = ss;
    __syncthreads();
    float inv = 32768.0f / fmaxf(sqrtf(scr[0][row] + scr[1][row] + scr[2][row] + scr[3][row]), 1e-12f);

#pragma unroll
    for (int j = 0; j < 16; ++j) {
        unsigned w1 = 0, w0 = 0;
#pragma unroll
        for (int t = 0; t < 4; ++t) {
            float qv = fminf(fmaxf(rintf(v[j * 4 + t] * inv), -32768.f), 32639.f);
            int af = (int)qv;
            int a1 = (af + 128) >> 8;
            int a0 = af - (a1 << 8);
            w1 |= (unsigned)(a1 & 255) << (8 * t);
            w0 |= (unsigned)(a0 & 255) << (8 * t);
        }
        int c0 = q * 64 + j * 4;
        int kg = c0 >> 4, dw = (c0 >> 2) & 3;
        *(unsigned*)&at[0][kg][row][dw * 4] = w1;
        *(unsigned*)&at[1][kg][row][dw * 4] = w0;
    }
    __syncthreads();

    const int tile = p0 >> 8, rhalf = (p0 >> 7) & 1;
    char* outb = Ag + (size_t)(fb * 256 + tile) * 131072;
#pragma unroll
    for (int it = 0; it < 8; ++it) {
        int id = tid + it * 512;              // 0..4095 16B chunks
        int pl = id >> 11, kg = (id >> 7) & 15, r2 = id & 127;
        i32x4 vv = *(const i32x4*)&at[pl][kg][r2][0];
        *(i32x4*)&outb[(size_t)pl * 65536 + kg * 4096 + (rhalf * 128 + r2) * 16] = vv;
    }
}

// ---------------- convA: keypoint descriptors -> i8 hi/lo planes, 32-col tiles ----------------
__global__ __launch_bounds__(256)
void convA_kernel(const float* __restrict__ kdesc, char* __restrict__ Bg) {
    __shared__ char bt[2][16][32][16];        // 16 KB
    __shared__ float scr[8][32];
    const int bid = blockIdx.x;               // 0..63
    const int b   = bid >> 5;
    const int nt  = bid & 31;
    const int n0  = nt * 32;
    const int tid = threadIdx.x;
    const int col = tid & 31;
    const int q   = tid >> 5;                 // 0..7 -> channels q*31..q*31+30

    const float* kp = kdesc + (size_t)(2 * b + 1) * CC * NN + n0 + col;
    float ss = 0.f;
    for (int i = 0; i < 31; ++i) {
        int c = q * 31 + i;
        float v = kp[(size_t)c * NN];
        ss += v * v;
    }
    scr[q][col] = ss;
    __syncthreads();
    float tot = 0.f;
#pragma unroll
    for (int k = 0; k < 8; ++k) tot += scr[k][col];
    float inv = 32768.0f / fmaxf(sqrtf(tot), 1e-12f);
    if (tid < 64) {                            // zero k-pad c=248..255
        int pl = tid >> 5, c2 = tid & 31;
        *(long*)&bt[pl][15][c2][8] = 0L;
    }
    __syncthreads();
    for (int i = 0; i < 31; ++i) {
        int c = q * 31 + i;
        float qq = fminf(fmaxf(rintf(kp[(size_t)c * NN] * inv), -32768.f), 32639.f);
        int af = (int)qq;
        int a1 = (af + 128) >> 8;
        int a0 = af - (a1 << 8);
        bt[0][c >> 4][col][c & 15] = (char)a1;
        bt[1][c >> 4][col][c & 15] = (char)a0;
    }
    __syncthreads();
    char* outb = Bg + (size_t)(b * 32 + nt) * 16384;
    const char* src = &bt[0][0][0][0];
#pragma unroll
    for (int it = 0; it < 4; ++it) {
        int id = tid + it * 256;              // 0..1023 16B chunks
        *(i32x4*)&outb[(size_t)id * 16] = *(const i32x4*)&src[(size_t)id * 16];
    }
}

// ---------------- fused i8 MFMA GEMM: fixed-base softmax (no max/merge), K=128 phases ----
// Block: 4 waves, BN=256 (64 n per wave), BM=1024 (32 mt of 32 rows), 64 phases (K=128).
// LDS: A ring 3 x 8192 [pl2][kk4][lhi2][lrow32][16] = 24 KB.
__global__ __launch_bounds__(256, 2)
void gemm_kernel(const char* __restrict__ Ag, const char* __restrict__ Bg,
                 float* __restrict__ partials) {
    __shared__ char lds[24576];

    const int bid  = blockIdx.x;              // 0..511
    const int xcd  = bid & 7;
    const int rest = bid >> 3;                // 0..63
    const int nchunk = rest & 3;
    const int pid  = xcd + 8 * (rest >> 2);   // 0..127 : A-panel sharers -> same XCD
    const int b      = pid >> 6;
    const int mchunk = pid & 63;              // BM = 1024

    const int lane = threadIdx.x & 63;
    const int w    = threadIdx.x >> 6;        // 0..3
    const int lrow = lane & 31;
    const int lhi  = lane >> 5;

    const char* atile0 = Ag + ((size_t)b * 256 + mchunk * 4) * 131072;  // 4 tiles of 256 rows
    const char* bb     = Bg + (size_t)(b * 32 + nchunk * 8 + w * 2) * 16384;  // wave's 2 n-tiles

    // ---- bc: BOTH planes, full K, 2 n-tiles -> 128 regs ----
    i32x4 bc[8][2][2];                         // [kk][pl][bp]
#pragma unroll
    for (int kk = 0; kk < 8; ++kk)
#pragma unroll
        for (int pl = 0; pl < 2; ++pl)
#pragma unroll
            for (int bp = 0; bp < 2; ++bp)
                bc[kk][pl][bp] = *(const i32x4*)(bb + bp * 16384 + pl * 8192
                                                 + (kk * 2 + lhi) * 512 + lrow * 16);

    // staging: phase p = (mt, half h); wave w stages chunks 2w, 2w+1 of 8 (pl,kkl) chunks
    auto ISSUE = [&](int p, int slotOff) {
        const int mtn = p >> 1, h = p & 1;
        const int tile = mtn >> 3, row0 = (mtn & 7) * 32;
#pragma unroll
        for (int i = 0; i < 2; ++i) {
            int c = w * 2 + i;
            int pl = c >> 2, kkl = c & 3;
            const char* src = atile0 + (size_t)tile * 131072 + pl * 65536
                            + (h * 8 + kkl * 2 + lhi) * 4096 + (row0 + lrow) * 16;
            char* dst = &lds[slotOff + pl * 4096 + kkl * 1024];
            __builtin_amdgcn_global_load_lds(
                (const __attribute__((address_space(1))) void*)src,
                (__attribute__((address_space(3))) void*)dst, 16, 0, 0);
        }
    };

    i32x16 accH[2], accX[2];
#pragma unroll
    for (int bp = 0; bp < 2; ++bp) { accH[bp] = (i32x16)(0); accX[bp] = (i32x16)(0); }
    float rz[2] = {0.f, 0.f}, rsu[2] = {0.f, 0.f}, rsv[2] = {0.f, 0.f};

    // score*log2(e) = (65536*H + 256*X) * 100*log2(e) / 2^30 ; fixed base 145 > max (144.27)
    const float S2 = 100.0f * 1.4426950408889634f / 1073741824.0f;
    const float cH = 65536.0f * S2;
    const float cX = 256.0f * S2;
    const float BASE = 145.0f;

    // fixed-base epilogue: no max, no rescale — plain accumulation
    auto EPI = [&](int mtq) {
        const int mbase = mchunk * 1024 + mtq * 32;
        const float ub = (float)((mbase & 255) + 4 * lhi);
        const float vcoord = (float)(mbase >> 8);
#pragma unroll
        for (int bp = 0; bp < 2; ++bp) {
            float tz = 0.f, tsur = 0.f;
#pragma unroll
            for (int r = 0; r < 16; ++r) {
                float e = fexp2(fmaf((float)accH[bp][r], cH,
                                fmaf((float)accX[bp][r], cX, -BASE)));
                tz += e;
                tsur = fmaf(e, (float)((r & 3) + 8 * (r >> 2)), tsur);
            }
            rz[bp] += tz;
            rsu[bp] += fmaf(ub, tz, tsur);
            rsv[bp] = fmaf(vcoord, tz, rsv[bp]);
            accH[bp] = (i32x16)(0); accX[bp] = (i32x16)(0);
        }
    };

    ISSUE(0, 0);
    ISSUE(1, 8192);
    int slotR = 0, slotW = 16384;              // phase p: read p%3, ISSUE(p+2) -> (p+2)%3

    for (int mt = 0; mt < 32; ++mt) {
#pragma unroll
        for (int h = 0; h < 2; ++h) {
            const int p = mt * 2 + h;
            if (p < 63) asm volatile("s_waitcnt vmcnt(2)" ::: "memory");  // phase-p slice done
            else        asm volatile("s_waitcnt vmcnt(0)" ::: "memory");
            asm volatile("s_barrier" ::: "memory");
            if (p + 2 < 64) ISSUE(p + 2, slotW);

            // group A: kk 0,1 frags (latency hides under EPI at mt boundaries)
            i32x4 a1_0 = *(const i32x4*)&lds[slotR + 0 * 1024 + lhi * 512 + lrow * 16];
            i32x4 a0_0 = *(const i32x4*)&lds[slotR + 4096 + 0 * 1024 + lhi * 512 + lrow * 16];
            i32x4 a1_1 = *(const i32x4*)&lds[slotR + 1 * 1024 + lhi * 512 + lrow * 16];
            i32x4 a0_1 = *(const i32x4*)&lds[slotR + 4096 + 1 * 1024 + lhi * 512 + lrow * 16];

            if (h == 0 && mt > 0) EPI(mt - 1);

            __builtin_amdgcn_s_setprio(1);
#pragma unroll
            for (int bp = 0; bp < 2; ++bp) {
                accH[bp] = __builtin_amdgcn_mfma_i32_32x32x32_i8(a1_0, bc[h * 4 + 0][0][bp], accH[bp], 0, 0, 0);
                accX[bp] = __builtin_amdgcn_mfma_i32_32x32x32_i8(a1_0, bc[h * 4 + 0][1][bp], accX[bp], 0, 0, 0);
                accX[bp] = __builtin_amdgcn_mfma_i32_32x32x32_i8(a0_0, bc[h * 4 + 0][0][bp], accX[bp], 0, 0, 0);
                accH[bp] = __builtin_amdgcn_mfma_i32_32x32x32_i8(a1_1, bc[h * 4 + 1][0][bp], accH[bp], 0, 0, 0);
                accX[bp] = __builtin_amdgcn_mfma_i32_32x32x32_i8(a1_1, bc[h * 4 + 1][1][bp], accX[bp], 0, 0, 0);
                accX[bp] = __builtin_amdgcn_mfma_i32_32x32x32_i8(a0_1, bc[h * 4 + 1][0][bp], accX[bp], 0, 0, 0);
            }
            __builtin_amdgcn_s_setprio(0);

            // group B: kk 2,3 frags (latency hides under group-A MFMAs)
            i32x4 a1_2 = *(const i32x4*)&lds[slotR + 2 * 1024 + lhi * 512 + lrow * 16];
            i32x4 a0_2 = *(const i32x4*)&lds[slotR + 4096 + 2 * 1024 + lhi * 512 + lrow * 16];
            i32x4 a1_3 = *(const i32x4*)&lds[slotR + 3 * 1024 + lhi * 512 + lrow * 16];
            i32x4 a0_3 = *(const i32x4*)&lds[slotR + 4096 + 3 * 1024 + lhi * 512 + lrow * 16];

            __builtin_amdgcn_s_setprio(1);
#pragma unroll
            for (int bp = 0; bp < 2; ++bp) {
                accH[bp] = __builtin_amdgcn_mfma_i32_32x32x32_i8(a1_2, bc[h * 4 + 2][0][bp], accH[bp], 0, 0, 0);
                accX[bp] = __builtin_amdgcn_mfma_i32_32x32x32_i8(a1_2, bc[h * 4 + 2][1][bp], accX[bp], 0, 0, 0);
                accX[bp] = __builtin_amdgcn_mfma_i32_32x32x32_i8(a0_2, bc[h * 4 + 2][0][bp], accX[bp], 0, 0, 0);
                accH[bp] = __builtin_amdgcn_mfma_i32_32x32x32_i8(a1_3, bc[h * 4 + 3][0][bp], accH[bp], 0, 0, 0);
                accX[bp] = __builtin_amdgcn_mfma_i32_32x32x32_i8(a1_3, bc[h * 4 + 3][1][bp], accX[bp], 0, 0, 0);
                accX[bp] = __builtin_amdgcn_mfma_i32_32x32x32_i8(a0_3, bc[h * 4 + 3][0][bp], accX[bp], 0, 0, 0);
            }
            __builtin_amdgcn_s_setprio(0);

            slotR = (slotR == 16384) ? 0 : slotR + 8192;
            slotW = (slotW == 16384) ? 0 : slotW + 8192;
        }
    }
    EPI(31);

    // ---- merge lane <-> lane+32 (plain sums), write partials (Z,Su,Sv) ----
#pragma unroll
    for (int bp = 0; bp < 2; ++bp) {
        rz[bp]  += __shfl_xor(rz[bp],  32, 64);
        rsu[bp] += __shfl_xor(rsu[bp], 32, 64);
        rsv[bp] += __shfl_xor(rsv[bp], 32, 64);
    }
    if (lane < 32) {
#pragma unroll
        for (int bp = 0; bp < 2; ++bp) {
            int n = nchunk * 256 + w * 64 + bp * 32 + lrow;
            size_t idxp = ((size_t)b * NN + n) * 64 + mchunk;
            ((float4*)partials)[idxp] = make_float4(rz[bp], rsu[bp], rsv[bp], 0.f);
        }
    }
}

// ---------------- combine: plain sum of 64 partials per (b,n) row ----------------
__global__ __launch_bounds__(256)
void combine_kernel(const float* __restrict__ partials,
                    const float* __restrict__ kscores,
                    const float* __restrict__ times,
                    float* __restrict__ out) {
    const int wg   = blockIdx.x * 4 + (threadIdx.x >> 6);  // 0..2047 = (b, n)
    const int lane = threadIdx.x & 63;
    const int b = wg >> 10, n = wg & 1023;
    const float4* pp = (const float4*)partials + (size_t)wg * 64;

    float4 p = pp[lane];
    float z = p.x, su = p.y, sv = p.z;
#pragma unroll
    for (int mask = 32; mask >= 1; mask >>= 1) {
        z  += __shfl_xor(z,  mask, 64);
        su += __shfl_xor(su, mask, 64);
        sv += __shfl_xor(sv, mask, 64);
    }

    if (lane == 0) {
        float u = su / z, v = sv / z;
        out[(size_t)wg * 2 + 0] = u;
        out[(size_t)wg * 2 + 1] = v;
        out[4096 + wg] = kscores[(size_t)(2 * b + 1) * NN + n];
        if (wg == 0) { out[6144] = 1.0f; out[6145] = 3.0f; }

        const float* timg = times + (size_t)(2 * b) * MM;
        float u0 = fminf(fmaxf(floorf(u), 0.f), 255.f);
        float v0 = fminf(fmaxf(floorf(v), 0.f), 255.f);
        float u1 = fminf(u0 + 1.f, 255.f);
        float v1 = fminf(v0 + 1.f, 255.f);
        float au = u - u0, av = v - v0;
        int u0i = (int)u0, u1i = (int)u1, v0i = (int)v0, v1i = (int)v1;
        float t00 = timg[v0i * 256 + u0i], t01 = timg[v0i * 256 + u1i];
        float t10 = timg[v1i * 256 + u0i], t11 = timg[v1i * 256 + u1i];
        float t = t00 * (1.f - au) * (1.f - av) + t01 * au * (1.f - av)
                + t10 * (1.f - au) * av + t11 * au * av;
        out[6146 + wg] = t;
    }
}

extern "C" void kernel_launch(void* const* d_in, const int* in_sizes, int n_in,
                              void* d_out, int out_size, void* d_ws, size_t ws_size,
                              hipStream_t stream) {
    const float* kscores = (const float*)d_in[0];
    const float* kdesc   = (const float*)d_in[1];
    const float* dense   = (const float*)d_in[2];
    const float* times   = (const float*)d_in[3];
    float* out = (float*)d_out;

    char* Ag = (char*)d_ws;                                   // 67,108,864 B
    char* Bg = Ag + (size_t)2 * 256 * 131072;                 //  1,048,576 B
    float* partials = (float*)(Bg + (size_t)2 * 32 * 16384);  //  2,097,152 B

    hipLaunchKernelGGL(convB_kernel,   dim3(1024), dim3(512), 0, stream, dense, Ag);
    hipLaunchKernelGGL(convA_kernel,   dim3(64),   dim3(256), 0, stream, kdesc, Bg);
    hipLaunchKernelGGL(gemm_kernel,    dim3(512),  dim3(256), 0, stream, Ag, Bg, partials);
    hipLaunchKernelGGL(combine_kernel, dim3(512),  dim3(256), 0, stream, partials, kscores, times, out);
}

// Round 17
// 120.446 us; speedup vs baseline: 1.3975x; 1.1351x over previous
//
#include <hip/hip_runtime.h>
#include <math.h>

typedef int i32x4 __attribute__((ext_vector_type(4)));
typedef int i32x16 __attribute__((ext_vector_type(16)));

#define CC 248
#define MM 65536
#define NN 1024

__device__ __forceinline__ float fexp2(float x) { return __builtin_amdgcn_exp2f(x); }

// ws: B_tiled [2][32 ntiles][pl 2][kg 16][col 32][16] (i8 hi/lo) = 1,048,576 B
//     partials [2][1024][512 mc] float4                          = 16,777,216 B

// ---------------- convA: keypoint descriptors -> i8 hi/lo planes, 32-col tiles ----------------
__global__ __launch_bounds__(256)
void convA_kernel(const float* __restrict__ kdesc, char* __restrict__ Bg) {
    __shared__ char bt[2][16][32][16];        // 16 KB
    __shared__ float scr[8][32];
    const int bid = blockIdx.x;               // 0..63
    const int b   = bid >> 5;
    const int nt  = bid & 31;
    const int n0  = nt * 32;
    const int tid = threadIdx.x;
    const int col = tid & 31;
    const int q   = tid >> 5;                 // 0..7 -> channels q*31..q*31+30

    const float* kp = kdesc + (size_t)(2 * b + 1) * CC * NN + n0 + col;
    float ss = 0.f;
    for (int i = 0; i < 31; ++i) {
        int c = q * 31 + i;
        float v = kp[(size_t)c * NN];
        ss += v * v;
    }
    scr[q][col] = ss;
    __syncthreads();
    float tot = 0.f;
#pragma unroll
    for (int k = 0; k < 8; ++k) tot += scr[k][col];
    float inv = 32768.0f / fmaxf(sqrtf(tot), 1e-12f);
    if (tid < 64) {                            // zero k-pad c=248..255
        int pl = tid >> 5, c2 = tid & 31;
        *(long*)&bt[pl][15][c2][8] = 0L;
    }
    __syncthreads();
    for (int i = 0; i < 31; ++i) {
        int c = q * 31 + i;
        float qq = fminf(fmaxf(rintf(kp[(size_t)c * NN] * inv), -32768.f), 32639.f);
        int af = (int)qq;
        int a1 = (af + 128) >> 8;
        int a0 = af - (a1 << 8);
        bt[0][c >> 4][col][c & 15] = (char)a1;
        bt[1][c >> 4][col][c & 15] = (char)a0;
    }
    __syncthreads();
    char* outb = Bg + (size_t)(b * 32 + nt) * 16384;
    const char* src = &bt[0][0][0][0];
#pragma unroll
    for (int it = 0; it < 4; ++it) {
        int id = tid + it * 256;              // 0..1023 16B chunks
        *(i32x4*)&outb[(size_t)id * 16] = *(const i32x4*)&src[(size_t)id * 16];
    }
}

// ---------------- fused quant + i8 MFMA GEMM: A quantized into LDS, barrier-free gemm ----
// Block: 256 thr (4 waves), 128 pixels (m) x ALL 1024 keypoints (n).
// LDS: at[pl 2][kg 16][row 128][16] = 64 KB at 0; scr (2x128 f32) at 65536. Total 66560 B.
// Phase 1: read fp32 pixels, norm, quantize into at[].  ONE barrier.
// Phase 2 (no barriers): per wave, 4 n-chunks of 64: bc (full-K, both planes) in 128 regs
//   from L2; 4 m-tiles of 32: 8 kk x 6 MFMA; fixed-base EPI; plain-sum partials.
__global__ __launch_bounds__(256, 2)
void fused_kernel(const float* __restrict__ dense, const char* __restrict__ Bg,
                  float* __restrict__ partials) {
    extern __shared__ char lds[];
    float* scr = (float*)(lds + 65536);

    const int bid = blockIdx.x;               // 0..1023
    const int fb  = bid >> 9;                 // 0..1 -> frame 2*fb
    const int p0  = (bid & 511) * 128;
    const int tid = threadIdx.x;

    // ======== phase 1: quantize 128 pixels into LDS ========
    {
        const int row = tid & 127;
        const int q   = tid >> 7;             // 0..1 -> channels q*124 .. +123
        const float* dptr = dense + (size_t)(2 * fb) * CC * MM + (size_t)(q * 124) * MM + p0 + row;
        float v[124];
        float ss = 0.f;
#pragma unroll
        for (int i = 0; i < 124; ++i) {
            v[i] = dptr[(size_t)i * MM];
            ss += v[i] * v[i];
        }
        scr[q * 128 + row] = ss;
        // zero k-pad (c=248..255 -> kg 15, bytes 8..15) for plane tid>>7
        *(long*)&lds[(tid >> 7) * 32768 + 15 * 2048 + (tid & 127) * 16 + 8] = 0L;
        __syncthreads();
        float inv = 32768.0f / fmaxf(sqrtf(scr[row] + scr[128 + row]), 1e-12f);
#pragma unroll
        for (int j = 0; j < 31; ++j) {
            unsigned w1 = 0, w0 = 0;
#pragma unroll
            for (int t = 0; t < 4; ++t) {
                float qv = fminf(fmaxf(rintf(v[j * 4 + t] * inv), -32768.f), 32639.f);
                int af = (int)qv;
                int a1 = (af + 128) >> 8;
                int a0 = af - (a1 << 8);
                w1 |= (unsigned)(a1 & 255) << (8 * t);
                w0 |= (unsigned)(a0 & 255) << (8 * t);
            }
            int c0 = q * 124 + j * 4;
            int kg = c0 >> 4, dw = (c0 >> 2) & 3;
            *(unsigned*)&lds[kg * 2048 + row * 16 + dw * 4] = w1;
            *(unsigned*)&lds[32768 + kg * 2048 + row * 16 + dw * 4] = w0;
        }
    }
    __syncthreads();   // at[] complete — last barrier in the kernel

    // ======== phase 2: barrier-free gemm ========
    const int lane = tid & 63;
    const int w    = tid >> 6;                // 0..3 -> n range w*256..+255
    const int lrow = lane & 31;
    const int lhi  = lane >> 5;

    const char* bbase = Bg + (size_t)(fb * 32) * 16384;

    // score*log2(e) = (65536*H + 256*X) * 100*log2(e) / 2^30 ; fixed base 145 > max
    const float S2 = 100.0f * 1.4426950408889634f / 1073741824.0f;
    const float cH = 65536.0f * S2;
    const float cX = 256.0f * S2;
    const float BASE = 145.0f;

    for (int nc = 0; nc < 4; ++nc) {
        // bc: both planes, full K, 2 n-tiles (64 n) -> 128 regs, from L2
        i32x4 bc[8][2][2];                     // [kk][pl][bp]
#pragma unroll
        for (int kk = 0; kk < 8; ++kk)
#pragma unroll
            for (int pl = 0; pl < 2; ++pl)
#pragma unroll
                for (int bp = 0; bp < 2; ++bp)
                    bc[kk][pl][bp] = *(const i32x4*)(bbase
                        + (size_t)(w * 8 + nc * 2 + bp) * 16384 + pl * 8192
                        + (kk * 2 + lhi) * 512 + lrow * 16);

        float rz[2] = {0.f, 0.f}, rsu[2] = {0.f, 0.f}, rsv[2] = {0.f, 0.f};

#pragma unroll
        for (int mt = 0; mt < 4; ++mt) {
            i32x16 accH[2], accX[2];
#pragma unroll
            for (int bp = 0; bp < 2; ++bp) { accH[bp] = (i32x16)(0); accX[bp] = (i32x16)(0); }

#pragma unroll
            for (int kk = 0; kk < 8; ++kk) {
                i32x4 a1 = *(const i32x4*)&lds[(kk * 2 + lhi) * 2048 + (mt * 32 + lrow) * 16];
                i32x4 a0 = *(const i32x4*)&lds[32768 + (kk * 2 + lhi) * 2048 + (mt * 32 + lrow) * 16];
                __builtin_amdgcn_s_setprio(1);
#pragma unroll
                for (int bp = 0; bp < 2; ++bp) {
                    accH[bp] = __builtin_amdgcn_mfma_i32_32x32x32_i8(a1, bc[kk][0][bp], accH[bp], 0, 0, 0);
                    accX[bp] = __builtin_amdgcn_mfma_i32_32x32x32_i8(a1, bc[kk][1][bp], accX[bp], 0, 0, 0);
                    accX[bp] = __builtin_amdgcn_mfma_i32_32x32x32_i8(a0, bc[kk][0][bp], accX[bp], 0, 0, 0);
                }
                __builtin_amdgcn_s_setprio(0);
            }

            // fixed-base EPI (no max, no rescale)
            const int mbase = p0 + mt * 32;
            const float ub = (float)((mbase & 255) + 4 * lhi);
            const float vcoord = (float)(mbase >> 8);
#pragma unroll
            for (int bp = 0; bp < 2; ++bp) {
                float tz = 0.f, tsur = 0.f;
#pragma unroll
                for (int r = 0; r < 16; ++r) {
                    float e = fexp2(fmaf((float)accH[bp][r], cH,
                                    fmaf((float)accX[bp][r], cX, -BASE)));
                    tz += e;
                    tsur = fmaf(e, (float)((r & 3) + 8 * (r >> 2)), tsur);
                }
                rz[bp] += tz;
                rsu[bp] += fmaf(ub, tz, tsur);
                rsv[bp] = fmaf(vcoord, tz, rsv[bp]);
            }
        }

        // merge lane <-> lane+32 (plain sums), write partials (Z,Su,Sv)
#pragma unroll
        for (int bp = 0; bp < 2; ++bp) {
            rz[bp]  += __shfl_xor(rz[bp],  32, 64);
            rsu[bp] += __shfl_xor(rsu[bp], 32, 64);
            rsv[bp] += __shfl_xor(rsv[bp], 32, 64);
        }
        if (lane < 32) {
#pragma unroll
            for (int bp = 0; bp < 2; ++bp) {
                int n = w * 256 + nc * 64 + bp * 32 + lrow;
                size_t idxp = ((size_t)(fb * NN + n)) * 512 + (bid & 511);
                ((float4*)partials)[idxp] = make_float4(rz[bp], rsu[bp], rsv[bp], 0.f);
            }
        }
    }
}

// ---------------- combine: plain sum of 512 partials per (b,n) row ----------------
__global__ __launch_bounds__(256)
void combine_kernel(const float* __restrict__ partials,
                    const float* __restrict__ kscores,
                    const float* __restrict__ times,
                    float* __restrict__ out) {
    const int wg   = blockIdx.x * 4 + (threadIdx.x >> 6);  // 0..2047 = (b, n)
    const int lane = threadIdx.x & 63;
    const int b = wg >> 10, n = wg & 1023;
    const float4* pp = (const float4*)partials + (size_t)wg * 512;

    float z = 0.f, su = 0.f, sv = 0.f;
#pragma unroll
    for (int k = 0; k < 8; ++k) {
        float4 p = pp[k * 64 + lane];
        z += p.x; su += p.y; sv += p.z;
    }
#pragma unroll
    for (int mask = 32; mask >= 1; mask >>= 1) {
        z  += __shfl_xor(z,  mask, 64);
        su += __shfl_xor(su, mask, 64);
        sv += __shfl_xor(sv, mask, 64);
    }

    if (lane == 0) {
        float u = su / z, v = sv / z;
        out[(size_t)wg * 2 + 0] = u;
        out[(size_t)wg * 2 + 1] = v;
        out[4096 + wg] = kscores[(size_t)(2 * b + 1) * NN + n];
        if (wg == 0) { out[6144] = 1.0f; out[6145] = 3.0f; }

        const float* timg = times + (size_t)(2 * b) * MM;
        float u0 = fminf(fmaxf(floorf(u), 0.f), 255.f);
        float v0 = fminf(fmaxf(floorf(v), 0.f), 255.f);
        float u1 = fminf(u0 + 1.f, 255.f);
        float v1 = fminf(v0 + 1.f, 255.f);
        float au = u - u0, av = v - v0;
        int u0i = (int)u0, u1i = (int)u1, v0i = (int)v0, v1i = (int)v1;
        float t00 = timg[v0i * 256 + u0i], t01 = timg[v0i * 256 + u1i];
        float t10 = timg[v1i * 256 + u0i], t11 = timg[v1i * 256 + u1i];
        float t = t00 * (1.f - au) * (1.f - av) + t01 * au * (1.f - av)
                + t10 * (1.f - au) * av + t11 * au * av;
        out[6146 + wg] = t;
    }
}

extern "C" void kernel_launch(void* const* d_in, const int* in_sizes, int n_in,
                              void* d_out, int out_size, void* d_ws, size_t ws_size,
                              hipStream_t stream) {
    const float* kscores = (const float*)d_in[0];
    const float* kdesc   = (const float*)d_in[1];
    const float* dense   = (const float*)d_in[2];
    const float* times   = (const float*)d_in[3];
    float* out = (float*)d_out;

    char* Bg = (char*)d_ws;                                   //  1,048,576 B
    float* partials = (float*)(Bg + (size_t)2 * 32 * 16384);  // 16,777,216 B

    hipFuncSetAttribute((const void*)fused_kernel,
                        hipFuncAttributeMaxDynamicSharedMemorySize, 66560);

    hipLaunchKernelGGL(convA_kernel,   dim3(64),   dim3(256), 0, stream, kdesc, Bg);
    hipLaunchKernelGGL(fused_kernel,   dim3(1024), dim3(256), 66560, stream, dense, Bg, partials);
    hipLaunchKernelGGL(combine_kernel, dim3(512),  dim3(256), 0, stream, partials, kscores, times, out);
}